// Round 1
// baseline (1199.760 us; speedup 1.0000x reference)
//
#include <hip/hip_runtime.h>

#define B_    128
#define T_    2048
#define OBS_  128
#define S_    128
#define OUT_  64
#define H_    64
#define NR    (B_*T_)            // 262144 rows
#define K_CH  32                 // chunk length
#define C_CH  64                 // number of chunks
#define VOFF  (NR*2*OUT_)        // 33554432 : cur_value offset in d_out
#define XFOFF (VOFF + NR)        // 33816576 : x_final offset in d_out

__device__ __forceinline__ unsigned short f2bf(float f){
  unsigned int u = __float_as_uint(f);
  u += 0x7FFFu + ((u >> 16) & 1u);
  return (unsigned short)(u >> 16);
}
__device__ __forceinline__ float bf2f(unsigned short h){
  return __uint_as_float(((unsigned int)h) << 16);
}

// ---------------- generic 128x128 @ 128x128 matmul: C[r*ldc+c] = sum_k A[r][k]B[k][c]
__global__ __launch_bounds__(256) void k_mm(const float* __restrict__ A,
                                            const float* __restrict__ B,
                                            float* __restrict__ C, int ldc){
  int e = blockIdx.x * 256 + threadIdx.x;     // 16384 output elems
  int r = e >> 7, c = e & 127;
  float acc = 0.f;
  #pragma unroll 4
  for (int k = 0; k < 128; ++k) acc += A[r*128 + k] * B[k*128 + c];
  C[r*ldc + c] = acc;
}

// ---------------- build M, Mt132 (transposed+padded), P, and copy Duy into Wcat, Cu into Cut132
__global__ __launch_bounds__(256) void k_build(const float* __restrict__ A_T,
                                               const float* __restrict__ A2,
                                               const float* __restrict__ A3,
                                               const float* __restrict__ A4,
                                               const float* __restrict__ Cu_T,
                                               const float* __restrict__ Duy_T,
                                               const float* __restrict__ dtp,
                                               float* __restrict__ M, float* __restrict__ Mt132,
                                               float* __restrict__ P, float* __restrict__ Wcat,
                                               float* __restrict__ Cut132){
  float dt = *dtp;
  float d2 = dt*dt*0.5f;
  float d3 = d2*dt*(1.f/3.f);
  float d4 = d3*dt*0.25f;
  int e = blockIdx.x * 256 + threadIdx.x;     // 0..16383
  int r = e >> 7, c = e & 127;
  float eye = (r == c) ? 1.f : 0.f;
  float m = eye + dt*A_T[e] + d2*A2[e] + d3*A3[e] + d4*A4[e];
  M[e] = m;
  Mt132[c*132 + r] = m;
  P[e] = dt*eye + d2*A_T[e] + d3*A2[e] + d4*A3[e];
  if (e < 128*64){
    int k = e >> 6, o = e & 63;
    Wcat[k*192 + 128 + o] = Duy_T[e];         // Duy columns of Wcat
    Cut132[o*132 + k]     = Cu_T[e];          // transposed Cu for phase3
  }
}

// ---------------- B1: [NR,128] @ Wcat[128,192] -> c (bf16, cols 0..127) and uy (bf16, cols 128..191)
__global__ __launch_bounds__(256) void k_b1(const float* __restrict__ obs,
                                            const float* __restrict__ Wcat,
                                            unsigned short* __restrict__ cbf,
                                            unsigned short* __restrict__ uybf){
  __shared__ float wlds[128*192];
  __shared__ float ylds[64*132];
  int tid = threadIdx.x;
  int row0 = blockIdx.x * 64;
  for (int li = tid*4; li < 128*192; li += 1024)
    *(float4*)&wlds[li] = *(const float4*)&Wcat[li];
  for (int li = tid*4; li < 64*128; li += 1024){
    int r = li >> 7, k = li & 127;
    *(float4*)&ylds[r*132 + k] = *(const float4*)&obs[(size_t)(row0 + r)*128 + k];
  }
  __syncthreads();
  int r0 = (tid >> 4) << 2, cb = tid & 15;
  for (int p = 0; p < 3; ++p){
    int colb = 64*p + 4*cb;
    float acc[4][4] = {};
    #pragma unroll 4
    for (int kk = 0; kk < 128; kk += 4){
      float4 w0 = *(const float4*)&wlds[(kk+0)*192 + colb];
      float4 w1 = *(const float4*)&wlds[(kk+1)*192 + colb];
      float4 w2 = *(const float4*)&wlds[(kk+2)*192 + colb];
      float4 w3 = *(const float4*)&wlds[(kk+3)*192 + colb];
      #pragma unroll
      for (int i = 0; i < 4; ++i){
        float4 yv = *(const float4*)&ylds[(r0+i)*132 + kk];
        acc[i][0] += yv.x*w0.x + yv.y*w1.x + yv.z*w2.x + yv.w*w3.x;
        acc[i][1] += yv.x*w0.y + yv.y*w1.y + yv.z*w2.y + yv.w*w3.y;
        acc[i][2] += yv.x*w0.z + yv.y*w1.z + yv.z*w2.z + yv.w*w3.z;
        acc[i][3] += yv.x*w0.w + yv.y*w1.w + yv.z*w2.w + yv.w*w3.w;
      }
    }
    #pragma unroll
    for (int i = 0; i < 4; ++i){
      size_t rr = (size_t)(row0 + r0 + i);
      ushort4 sv;
      sv.x = f2bf(acc[i][0]); sv.y = f2bf(acc[i][1]);
      sv.z = f2bf(acc[i][2]); sv.w = f2bf(acc[i][3]);
      if (p < 2) *(ushort4*)&cbf[rr*128 + colb]        = sv;
      else       *(ushort4*)&uybf[rr*64 + (colb-128)]  = sv;
    }
  }
}

// ---------------- B2: value MLP + log_stds broadcast
__global__ __launch_bounds__(256) void k_b2(const float* __restrict__ obs,
                                            const float* __restrict__ W0, const float* __restrict__ b0,
                                            const float* __restrict__ W1, const float* __restrict__ b1,
                                            const float* __restrict__ W2, const float* __restrict__ b2,
                                            const float* __restrict__ ls, float* __restrict__ out){
  __shared__ float ylds[64*132];
  __shared__ float w0l[64*132];
  __shared__ float h0l[64*68];
  __shared__ float w1l[64*68];
  __shared__ float h1l[64*68];
  __shared__ float w2l[64];
  __shared__ float b0l[64], b1l[64], lsl[64];
  int tid = threadIdx.x;
  int row0 = blockIdx.x * 64;
  for (int li = tid*4; li < 64*128; li += 1024){
    int r = li >> 7, k = li & 127;
    *(float4*)&ylds[r*132 + k] = *(const float4*)&obs[(size_t)(row0 + r)*128 + k];
    *(float4*)&w0l [r*132 + k] = *(const float4*)&W0[li];
  }
  for (int li = tid*4; li < 64*64; li += 1024){
    int r = li >> 6, k = li & 63;
    *(float4*)&w1l[r*68 + k] = *(const float4*)&W1[li];
  }
  if (tid < 64){ w2l[tid] = W2[tid]; b0l[tid] = b0[tid]; b1l[tid] = b1[tid]; lsl[tid] = ls[tid]; }
  __syncthreads();
  int r0 = (tid >> 4) << 2, hb = tid & 15;
  { // layer 0
    float acc[4][4] = {};
    #pragma unroll 4
    for (int kk = 0; kk < 128; kk += 4){
      float4 wa = *(const float4*)&w0l[(hb     )*132 + kk];
      float4 wb = *(const float4*)&w0l[(hb + 16)*132 + kk];
      float4 wc = *(const float4*)&w0l[(hb + 32)*132 + kk];
      float4 wd = *(const float4*)&w0l[(hb + 48)*132 + kk];
      #pragma unroll
      for (int i = 0; i < 4; ++i){
        float4 yv = *(const float4*)&ylds[(r0+i)*132 + kk];
        acc[i][0] += yv.x*wa.x + yv.y*wa.y + yv.z*wa.z + yv.w*wa.w;
        acc[i][1] += yv.x*wb.x + yv.y*wb.y + yv.z*wb.z + yv.w*wb.w;
        acc[i][2] += yv.x*wc.x + yv.y*wc.y + yv.z*wc.z + yv.w*wc.w;
        acc[i][3] += yv.x*wd.x + yv.y*wd.y + yv.z*wd.z + yv.w*wd.w;
      }
    }
    #pragma unroll
    for (int i = 0; i < 4; ++i){
      #pragma unroll
      for (int j = 0; j < 4; ++j)
        h0l[(r0+i)*68 + hb + 16*j] = tanhf(acc[i][j] + b0l[hb + 16*j]);
    }
  }
  __syncthreads();
  { // layer 1
    float acc[4][4] = {};
    #pragma unroll 4
    for (int kk = 0; kk < 64; kk += 4){
      float4 wa = *(const float4*)&w1l[(hb     )*68 + kk];
      float4 wb = *(const float4*)&w1l[(hb + 16)*68 + kk];
      float4 wc = *(const float4*)&w1l[(hb + 32)*68 + kk];
      float4 wd = *(const float4*)&w1l[(hb + 48)*68 + kk];
      #pragma unroll
      for (int i = 0; i < 4; ++i){
        float4 hv = *(const float4*)&h0l[(r0+i)*68 + kk];
        acc[i][0] += hv.x*wa.x + hv.y*wa.y + hv.z*wa.z + hv.w*wa.w;
        acc[i][1] += hv.x*wb.x + hv.y*wb.y + hv.z*wb.z + hv.w*wb.w;
        acc[i][2] += hv.x*wc.x + hv.y*wc.y + hv.z*wc.z + hv.w*wc.w;
        acc[i][3] += hv.x*wd.x + hv.y*wd.y + hv.z*wd.z + hv.w*wd.w;
      }
    }
    #pragma unroll
    for (int i = 0; i < 4; ++i){
      #pragma unroll
      for (int j = 0; j < 4; ++j)
        h1l[(r0+i)*68 + hb + 16*j] = tanhf(acc[i][j] + b1l[hb + 16*j]);
    }
  }
  __syncthreads();
  if (tid < 64){ // value head
    float acc = b2[0];
    #pragma unroll
    for (int kk = 0; kk < 64; kk += 4){
      float4 hv = *(const float4*)&h1l[tid*68 + kk];
      float4 wv = *(const float4*)&w2l[kk];
      acc += hv.x*wv.x + hv.y*wv.y + hv.z*wv.z + hv.w*wv.w;
    }
    out[(size_t)VOFF + row0 + tid] = acc;
  }
  for (int li = tid; li < 64*64; li += 256){
    int r = li >> 6, o = li & 63;
    out[(size_t)(row0 + r)*128 + 64 + o] = lsl[o];
  }
}

// ---------------- phase 1: per-chunk zero-init scan -> deltas D[ci][b][s]
__global__ __launch_bounds__(256) void k_phase1(const unsigned short* __restrict__ cbf,
                                                const float* __restrict__ Mt132g,
                                                float* __restrict__ Dd){
  __shared__ float mt[128*132];
  __shared__ float xl[32*128];
  int tid = threadIdx.x;
  int ci = blockIdx.x >> 2, bi = blockIdx.x & 3;
  int b0 = bi * 32, t0 = ci * K_CH;
  for (int li = tid*4; li < 128*132; li += 1024)
    *(float4*)&mt[li] = *(const float4*)&Mt132g[li];
  for (int li = tid; li < 32*128; li += 256) xl[li] = 0.f;
  int r0 = (tid >> 5) << 2, cb = tid & 31;
  unsigned short cn[4][4];
  #pragma unroll
  for (int i = 0; i < 4; ++i){
    size_t rowb = ((size_t)(b0 + r0 + i) * T_ + t0);
    #pragma unroll
    for (int j = 0; j < 4; ++j) cn[i][j] = cbf[rowb*128 + cb + 32*j];
  }
  __syncthreads();
  for (int s = 0; s < K_CH; ++s){
    float ax[4][4];
    #pragma unroll
    for (int i = 0; i < 4; ++i)
      #pragma unroll
      for (int j = 0; j < 4; ++j) ax[i][j] = bf2f(cn[i][j]);
    if (s + 1 < K_CH){
      #pragma unroll
      for (int i = 0; i < 4; ++i){
        size_t rowb = ((size_t)(b0 + r0 + i) * T_ + (t0 + s + 1));
        #pragma unroll
        for (int j = 0; j < 4; ++j) cn[i][j] = cbf[rowb*128 + cb + 32*j];
      }
    }
    #pragma unroll 4
    for (int kk = 0; kk < 128; kk += 4){
      float4 m0 = *(const float4*)&mt[(cb     )*132 + kk];
      float4 m1 = *(const float4*)&mt[(cb + 32)*132 + kk];
      float4 m2 = *(const float4*)&mt[(cb + 64)*132 + kk];
      float4 m3 = *(const float4*)&mt[(cb + 96)*132 + kk];
      #pragma unroll
      for (int i = 0; i < 4; ++i){
        float4 xv = *(const float4*)&xl[(r0+i)*128 + kk];
        ax[i][0] += xv.x*m0.x + xv.y*m0.y + xv.z*m0.z + xv.w*m0.w;
        ax[i][1] += xv.x*m1.x + xv.y*m1.y + xv.z*m1.z + xv.w*m1.w;
        ax[i][2] += xv.x*m2.x + xv.y*m2.y + xv.z*m2.z + xv.w*m2.w;
        ax[i][3] += xv.x*m3.x + xv.y*m3.y + xv.z*m3.z + xv.w*m3.w;
      }
    }
    __syncthreads();
    if (s + 1 == K_CH){
      #pragma unroll
      for (int i = 0; i < 4; ++i)
        #pragma unroll
        for (int j = 0; j < 4; ++j)
          Dd[(size_t)ci*16384 + (size_t)(b0 + r0 + i)*128 + cb + 32*j] = ax[i][j];
    } else {
      #pragma unroll
      for (int i = 0; i < 4; ++i){
        xl[(r0+i)*128 + cb     ] = ax[i][0];
        xl[(r0+i)*128 + cb + 32] = ax[i][1];
        xl[(r0+i)*128 + cb + 64] = ax[i][2];
        xl[(r0+i)*128 + cb + 96] = ax[i][3];
      }
      __syncthreads();
    }
  }
}

// ---------------- combine: sequential over 64 chunks, parallel over batch rows
__global__ __launch_bounds__(256) void k_combine(const float* __restrict__ Mk,
                                                 const float* __restrict__ Dd,
                                                 const float* __restrict__ x0,
                                                 float* __restrict__ XS,
                                                 float* __restrict__ xfin){
  __shared__ float xl[128];
  __shared__ float pl[256];
  int tid = threadIdx.x;
  int b = blockIdx.x;
  int c = tid & 127, h = tid >> 7;
  float mreg[64];
  #pragma unroll
  for (int j = 0; j < 64; ++j) mreg[j] = Mk[(64*h + j)*128 + c];
  if (tid < 128) xl[tid] = x0[(size_t)b*128 + tid];
  __syncthreads();
  for (int i = 0; i < C_CH; ++i){
    if (tid < 128) XS[(size_t)i*16384 + (size_t)b*128 + tid] = xl[tid];
    float part = 0.f;
    #pragma unroll
    for (int jj = 0; jj < 64; jj += 4){
      float4 xv = *(const float4*)&xl[64*h + jj];
      part += xv.x*mreg[jj] + xv.y*mreg[jj+1] + xv.z*mreg[jj+2] + xv.w*mreg[jj+3];
    }
    pl[tid] = part;
    __syncthreads();
    if (tid < 128)
      xl[tid] = pl[tid] + pl[tid + 128] + Dd[(size_t)i*16384 + (size_t)b*128 + tid];
    __syncthreads();
  }
  if (tid < 128) xfin[(size_t)b*128 + tid] = xl[tid];
}

// ---------------- phase 3: replay with true inits, fused action output
__global__ __launch_bounds__(256) void k_phase3(const unsigned short* __restrict__ cbf,
                                                const unsigned short* __restrict__ uybf,
                                                const float* __restrict__ Mt132g,
                                                const float* __restrict__ Cut132g,
                                                const float* __restrict__ XS,
                                                float* __restrict__ out){
  __shared__ float mt[128*132];
  __shared__ float cut[64*132];
  __shared__ float xl[32*128];
  int tid = threadIdx.x;
  int ci = blockIdx.x >> 2, bi = blockIdx.x & 3;
  int b0 = bi * 32, t0 = ci * K_CH;
  for (int li = tid*4; li < 128*132; li += 1024)
    *(float4*)&mt[li] = *(const float4*)&Mt132g[li];
  for (int li = tid*4; li < 64*132; li += 1024)
    *(float4*)&cut[li] = *(const float4*)&Cut132g[li];
  for (int li = tid; li < 32*128; li += 256){
    int r = li >> 7, c2 = li & 127;
    xl[li] = XS[(size_t)ci*16384 + (size_t)(b0 + r)*128 + c2];
  }
  int r0 = (tid >> 5) << 2, cb = tid & 31;
  unsigned short cn[4][4], un[4][2];
  #pragma unroll
  for (int i = 0; i < 4; ++i){
    size_t rowb = ((size_t)(b0 + r0 + i) * T_ + t0);
    #pragma unroll
    for (int j = 0; j < 4; ++j) cn[i][j] = cbf[rowb*128 + cb + 32*j];
    un[i][0] = uybf[rowb*64 + cb];
    un[i][1] = uybf[rowb*64 + cb + 32];
  }
  __syncthreads();
  for (int s = 0; s < K_CH; ++s){
    float ax[4][4], au[4][2];
    #pragma unroll
    for (int i = 0; i < 4; ++i){
      #pragma unroll
      for (int j = 0; j < 4; ++j) ax[i][j] = bf2f(cn[i][j]);
      au[i][0] = bf2f(un[i][0]);
      au[i][1] = bf2f(un[i][1]);
    }
    if (s + 1 < K_CH){
      #pragma unroll
      for (int i = 0; i < 4; ++i){
        size_t rowb = ((size_t)(b0 + r0 + i) * T_ + (t0 + s + 1));
        #pragma unroll
        for (int j = 0; j < 4; ++j) cn[i][j] = cbf[rowb*128 + cb + 32*j];
        un[i][0] = uybf[rowb*64 + cb];
        un[i][1] = uybf[rowb*64 + cb + 32];
      }
    }
    #pragma unroll 2
    for (int kk = 0; kk < 128; kk += 4){
      float4 m0 = *(const float4*)&mt[(cb     )*132 + kk];
      float4 m1 = *(const float4*)&mt[(cb + 32)*132 + kk];
      float4 m2 = *(const float4*)&mt[(cb + 64)*132 + kk];
      float4 m3 = *(const float4*)&mt[(cb + 96)*132 + kk];
      float4 c0 = *(const float4*)&cut[(cb     )*132 + kk];
      float4 c1 = *(const float4*)&cut[(cb + 32)*132 + kk];
      #pragma unroll
      for (int i = 0; i < 4; ++i){
        float4 xv = *(const float4*)&xl[(r0+i)*128 + kk];
        ax[i][0] += xv.x*m0.x + xv.y*m0.y + xv.z*m0.z + xv.w*m0.w;
        ax[i][1] += xv.x*m1.x + xv.y*m1.y + xv.z*m1.z + xv.w*m1.w;
        ax[i][2] += xv.x*m2.x + xv.y*m2.y + xv.z*m2.z + xv.w*m2.w;
        ax[i][3] += xv.x*m3.x + xv.y*m3.y + xv.z*m3.z + xv.w*m3.w;
        au[i][0] += xv.x*c0.x + xv.y*c0.y + xv.z*c0.z + xv.w*c0.w;
        au[i][1] += xv.x*c1.x + xv.y*c1.y + xv.z*c1.z + xv.w*c1.w;
      }
    }
    int t = t0 + s;
    #pragma unroll
    for (int i = 0; i < 4; ++i){
      size_t ro = ((size_t)(b0 + r0 + i) * T_ + t) * 128;
      out[ro + cb]      = au[i][0];
      out[ro + cb + 32] = au[i][1];
    }
    __syncthreads();
    if (s + 1 < K_CH){
      #pragma unroll
      for (int i = 0; i < 4; ++i){
        xl[(r0+i)*128 + cb     ] = ax[i][0];
        xl[(r0+i)*128 + cb + 32] = ax[i][1];
        xl[(r0+i)*128 + cb + 64] = ax[i][2];
        xl[(r0+i)*128 + cb + 96] = ax[i][3];
      }
      __syncthreads();
    }
  }
}

extern "C" void kernel_launch(void* const* d_in, const int* in_sizes, int n_in,
                              void* d_out, int out_size, void* d_ws, size_t ws_size,
                              hipStream_t stream){
  const float* obs  = (const float*)d_in[0];
  const float* x0   = (const float*)d_in[1];
  const float* A_T  = (const float*)d_in[2];
  const float* By_T = (const float*)d_in[3];
  const float* Cu_T = (const float*)d_in[4];
  const float* Duy_T= (const float*)d_in[5];
  const float* ls   = (const float*)d_in[6];
  const float* W0   = (const float*)d_in[7];
  const float* b0   = (const float*)d_in[8];
  const float* W1   = (const float*)d_in[9];
  const float* b1   = (const float*)d_in[10];
  const float* W2   = (const float*)d_in[11];
  const float* b2   = (const float*)d_in[12];
  const float* dt   = (const float*)d_in[13];
  float* out = (float*)d_out;

  char* ws = (char*)d_ws;
  unsigned short* cbf  = (unsigned short*)(ws + 0);           // 67108864 B
  unsigned short* uybf = (unsigned short*)(ws + 67108864);    // 33554432 B
  float* A2     = (float*)(ws + 100663296);                   // 65536 each
  float* A3     = (float*)(ws + 100728832);
  float* A4     = (float*)(ws + 100794368);
  float* Mm     = (float*)(ws + 100859904);
  float* Pp     = (float*)(ws + 100925440);
  float* Mk     = (float*)(ws + 100990976);
  float* sq1    = (float*)(ws + 101056512);
  float* sq2    = (float*)(ws + 101122048);
  float* Mt132  = (float*)(ws + 101187584);                   // 67584 B
  float* Wcat   = (float*)(ws + 101255168);                   // 98304 B
  float* Cut132 = (float*)(ws + 101353472);                   // 33792 B
  float* Dd     = (float*)(ws + 101387264);                   // 4194304 B
  float* XS     = (float*)(ws + 105581568);                   // 4194304 B

  // ---- small setup chain
  k_mm<<<64, 256, 0, stream>>>(A_T, A_T, A2, 128);
  k_mm<<<64, 256, 0, stream>>>(A2, A_T, A3, 128);
  k_mm<<<64, 256, 0, stream>>>(A2, A2, A4, 128);
  k_build<<<64, 256, 0, stream>>>(A_T, A2, A3, A4, Cu_T, Duy_T, dt, Mm, Mt132, Pp, Wcat, Cut132);
  k_mm<<<64, 256, 0, stream>>>(By_T, Pp, Wcat, 192);          // G -> Wcat cols 0..127
  k_mm<<<64, 256, 0, stream>>>(Mm, Mm, sq1, 128);             // M^2
  k_mm<<<64, 256, 0, stream>>>(sq1, sq1, sq2, 128);           // M^4
  k_mm<<<64, 256, 0, stream>>>(sq2, sq2, sq1, 128);           // M^8
  k_mm<<<64, 256, 0, stream>>>(sq1, sq1, sq2, 128);           // M^16
  k_mm<<<64, 256, 0, stream>>>(sq2, sq2, Mk, 128);            // M^32

  // ---- big parallel work
  k_b1<<<NR/64, 256, 0, stream>>>(obs, Wcat, cbf, uybf);
  k_phase1<<<C_CH*4, 256, 0, stream>>>(cbf, Mt132, Dd);
  k_combine<<<B_, 256, 0, stream>>>(Mk, Dd, x0, XS, out + XFOFF);
  k_phase3<<<C_CH*4, 256, 0, stream>>>(cbf, uybf, Mt132, Cut132, XS, out);
  k_b2<<<NR/64, 256, 0, stream>>>(obs, W0, b0, W1, b1, W2, b2, ls, out);
}

// Round 2
// 991.939 us; speedup vs baseline: 1.2095x; 1.2095x over previous
//
#include <hip/hip_runtime.h>

#define B_    128
#define T_    2048
#define OBS_  128
#define S_    128
#define OUT_  64
#define H_    64
#define NR    (B_*T_)            // 262144 rows
#define K_CH  32                 // chunk length
#define C_CH  64                 // number of chunks
#define VOFF  (NR*2*OUT_)        // 33554432 : cur_value offset in d_out
#define XFOFF (VOFF + NR)        // 33816576 : x_final offset in d_out

typedef __attribute__((ext_vector_type(8))) short short8v;   // 8 bf16 (4 VGPRs)
typedef __attribute__((ext_vector_type(4))) float f32x4;

__device__ __forceinline__ unsigned short f2bf(float f){
  unsigned int u = __float_as_uint(f);
  u += 0x7FFFu + ((u >> 16) & 1u);
  return (unsigned short)(u >> 16);
}
__device__ __forceinline__ float bf2f(unsigned short h){
  return __uint_as_float(((unsigned int)h) << 16);
}

// ---------------- generic 128x128 @ 128x128 matmul: C[r*ldc+c] = sum_k A[r][k]B[k][c]
__global__ __launch_bounds__(256) void k_mm(const float* __restrict__ A,
                                            const float* __restrict__ B,
                                            float* __restrict__ C, int ldc){
  int e = blockIdx.x * 256 + threadIdx.x;     // 16384 output elems
  int r = e >> 7, c = e & 127;
  float acc = 0.f;
  #pragma unroll 4
  for (int k = 0; k < 128; ++k) acc += A[r*128 + k] * B[k*128 + c];
  C[r*ldc + c] = acc;
}

// ---------------- build M, Mt132 (transposed+padded), P, and copy Duy into Wcat, Cu into Cut132
__global__ __launch_bounds__(256) void k_build(const float* __restrict__ A_T,
                                               const float* __restrict__ A2,
                                               const float* __restrict__ A3,
                                               const float* __restrict__ A4,
                                               const float* __restrict__ Cu_T,
                                               const float* __restrict__ Duy_T,
                                               const float* __restrict__ dtp,
                                               float* __restrict__ M, float* __restrict__ Mt132,
                                               float* __restrict__ P, float* __restrict__ Wcat,
                                               float* __restrict__ Cut132){
  float dt = *dtp;
  float d2 = dt*dt*0.5f;
  float d3 = d2*dt*(1.f/3.f);
  float d4 = d3*dt*0.25f;
  int e = blockIdx.x * 256 + threadIdx.x;     // 0..16383
  int r = e >> 7, c = e & 127;
  float eye = (r == c) ? 1.f : 0.f;
  float m = eye + dt*A_T[e] + d2*A2[e] + d3*A3[e] + d4*A4[e];
  M[e] = m;
  Mt132[c*132 + r] = m;
  P[e] = dt*eye + d2*A_T[e] + d3*A2[e] + d4*A3[e];
  if (e < 128*64){
    int k = e >> 6, o = e & 63;
    Wcat[k*192 + 128 + o] = Duy_T[e];         // Duy columns of Wcat
    Cut132[o*132 + k]     = Cu_T[e];          // transposed Cu for phase3
  }
}

// ---------------- convert Wcat f32 [128,192] -> bf16
__global__ __launch_bounds__(256) void k_cvtw(const float* __restrict__ Wcat,
                                              unsigned short* __restrict__ Wbf){
  int e = blockIdx.x * 256 + threadIdx.x;     // 0..24575
  Wbf[e] = f2bf(Wcat[e]);
}

// ---------------- B1 (MFMA): cuy[NR,192] = bf16( obs[NR,128] @ Wbf[128,192] )
// cols 0..127 = c (y@G), cols 128..191 = uy (y@Duy)
__global__ __launch_bounds__(256) void k_b1(const float* __restrict__ obs,
                                            const unsigned short* __restrict__ Wbf,
                                            unsigned short* __restrict__ cuy){
  __shared__ unsigned short ct[128*200];      // 50 KiB repack tile (pad 192->200)
  int tid = threadIdx.x;
  int lane = tid & 63, w = tid >> 6;
  size_t row0 = (size_t)blockIdx.x * 128;
  int colbase = w * 48;
  int lr = lane & 15;                         // A row / B,D col within frag
  int lk = (lane >> 4) * 8;                   // K offset within frag

  // B fragments: 3 col-frags x 4 k-frags, kept in registers (48 VGPRs)
  short8v bfrag[3][4];
  #pragma unroll
  for (int cf = 0; cf < 3; ++cf)
    #pragma unroll
    for (int kk = 0; kk < 4; ++kk){
      short8v b;
      #pragma unroll
      for (int j = 0; j < 8; ++j)
        b[j] = (short)Wbf[(size_t)(kk*32 + lk + j)*192 + (colbase + cf*16 + lr)];
      bfrag[cf][kk] = b;
    }

  for (int rf = 0; rf < 8; ++rf){
    f32x4 acc0 = {0.f,0.f,0.f,0.f}, acc1 = {0.f,0.f,0.f,0.f}, acc2 = {0.f,0.f,0.f,0.f};
    const float* arow = obs + (row0 + (size_t)(rf*16 + lr)) * 128;
    #pragma unroll
    for (int kk = 0; kk < 4; ++kk){
      float4 a0 = *(const float4*)&arow[kk*32 + lk];
      float4 a1 = *(const float4*)&arow[kk*32 + lk + 4];
      short8v af;
      af[0] = (short)f2bf(a0.x); af[1] = (short)f2bf(a0.y);
      af[2] = (short)f2bf(a0.z); af[3] = (short)f2bf(a0.w);
      af[4] = (short)f2bf(a1.x); af[5] = (short)f2bf(a1.y);
      af[6] = (short)f2bf(a1.z); af[7] = (short)f2bf(a1.w);
      acc0 = __builtin_amdgcn_mfma_f32_16x16x32_bf16(af, bfrag[0][kk], acc0, 0, 0, 0);
      acc1 = __builtin_amdgcn_mfma_f32_16x16x32_bf16(af, bfrag[1][kk], acc1, 0, 0, 0);
      acc2 = __builtin_amdgcn_mfma_f32_16x16x32_bf16(af, bfrag[2][kk], acc2, 0, 0, 0);
    }
    int orow = rf*16 + (lane >> 4)*4;         // D: col=lane&15, row=(lane>>4)*4+j
    #pragma unroll
    for (int j = 0; j < 4; ++j){
      ct[(orow + j)*200 + colbase      + lr] = f2bf(acc0[j]);
      ct[(orow + j)*200 + colbase + 16 + lr] = f2bf(acc1[j]);
      ct[(orow + j)*200 + colbase + 32 + lr] = f2bf(acc2[j]);
    }
  }
  __syncthreads();
  // coalesced ushort8 (16B) stores: 128 rows x 24 segs
  for (int li = tid; li < 128*24; li += 256){
    int r = li / 24, seg = li % 24;
    *(uint4*)&cuy[(row0 + r)*192 + seg*8] = *(const uint4*)&ct[r*200 + seg*8];
  }
}

// ---------------- B2: value MLP + log_stds broadcast
__global__ __launch_bounds__(256) void k_b2(const float* __restrict__ obs,
                                            const float* __restrict__ W0, const float* __restrict__ b0,
                                            const float* __restrict__ W1, const float* __restrict__ b1,
                                            const float* __restrict__ W2, const float* __restrict__ b2,
                                            const float* __restrict__ ls, float* __restrict__ out){
  __shared__ float ylds[64*132];
  __shared__ float w0l[64*132];
  __shared__ float h0l[64*68];
  __shared__ float w1l[64*68];
  __shared__ float h1l[64*68];
  __shared__ float w2l[64];
  __shared__ float b0l[64], b1l[64], lsl[64];
  int tid = threadIdx.x;
  int row0 = blockIdx.x * 64;
  for (int li = tid*4; li < 64*128; li += 1024){
    int r = li >> 7, k = li & 127;
    *(float4*)&ylds[r*132 + k] = *(const float4*)&obs[(size_t)(row0 + r)*128 + k];
    *(float4*)&w0l [r*132 + k] = *(const float4*)&W0[li];
  }
  for (int li = tid*4; li < 64*64; li += 1024){
    int r = li >> 6, k = li & 63;
    *(float4*)&w1l[r*68 + k] = *(const float4*)&W1[li];
  }
  if (tid < 64){ w2l[tid] = W2[tid]; b0l[tid] = b0[tid]; b1l[tid] = b1[tid]; lsl[tid] = ls[tid]; }
  __syncthreads();
  int r0 = (tid >> 4) << 2, hb = tid & 15;
  { // layer 0
    float acc[4][4] = {};
    #pragma unroll 4
    for (int kk = 0; kk < 128; kk += 4){
      float4 wa = *(const float4*)&w0l[(hb     )*132 + kk];
      float4 wb = *(const float4*)&w0l[(hb + 16)*132 + kk];
      float4 wc = *(const float4*)&w0l[(hb + 32)*132 + kk];
      float4 wd = *(const float4*)&w0l[(hb + 48)*132 + kk];
      #pragma unroll
      for (int i = 0; i < 4; ++i){
        float4 yv = *(const float4*)&ylds[(r0+i)*132 + kk];
        acc[i][0] += yv.x*wa.x + yv.y*wa.y + yv.z*wa.z + yv.w*wa.w;
        acc[i][1] += yv.x*wb.x + yv.y*wb.y + yv.z*wb.z + yv.w*wb.w;
        acc[i][2] += yv.x*wc.x + yv.y*wc.y + yv.z*wc.z + yv.w*wc.w;
        acc[i][3] += yv.x*wd.x + yv.y*wd.y + yv.z*wd.z + yv.w*wd.w;
      }
    }
    #pragma unroll
    for (int i = 0; i < 4; ++i){
      #pragma unroll
      for (int j = 0; j < 4; ++j)
        h0l[(r0+i)*68 + hb + 16*j] = tanhf(acc[i][j] + b0l[hb + 16*j]);
    }
  }
  __syncthreads();
  { // layer 1
    float acc[4][4] = {};
    #pragma unroll 4
    for (int kk = 0; kk < 64; kk += 4){
      float4 wa = *(const float4*)&w1l[(hb     )*68 + kk];
      float4 wb = *(const float4*)&w1l[(hb + 16)*68 + kk];
      float4 wc = *(const float4*)&w1l[(hb + 32)*68 + kk];
      float4 wd = *(const float4*)&w1l[(hb + 48)*68 + kk];
      #pragma unroll
      for (int i = 0; i < 4; ++i){
        float4 hv = *(const float4*)&h0l[(r0+i)*68 + kk];
        acc[i][0] += hv.x*wa.x + hv.y*wa.y + hv.z*wa.z + hv.w*wa.w;
        acc[i][1] += hv.x*wb.x + hv.y*wb.y + hv.z*wb.z + hv.w*wb.w;
        acc[i][2] += hv.x*wc.x + hv.y*wc.y + hv.z*wc.z + hv.w*wc.w;
        acc[i][3] += hv.x*wd.x + hv.y*wd.y + hv.z*wd.z + hv.w*wd.w;
      }
    }
    #pragma unroll
    for (int i = 0; i < 4; ++i){
      #pragma unroll
      for (int j = 0; j < 4; ++j)
        h1l[(r0+i)*68 + hb + 16*j] = tanhf(acc[i][j] + b1l[hb + 16*j]);
    }
  }
  __syncthreads();
  if (tid < 64){ // value head
    float acc = b2[0];
    #pragma unroll
    for (int kk = 0; kk < 64; kk += 4){
      float4 hv = *(const float4*)&h1l[tid*68 + kk];
      float4 wv = *(const float4*)&w2l[kk];
      acc += hv.x*wv.x + hv.y*wv.y + hv.z*wv.z + hv.w*wv.w;
    }
    out[(size_t)VOFF + row0 + tid] = acc;
  }
  for (int li = tid; li < 64*64; li += 256){
    int r = li >> 6, o = li & 63;
    out[(size_t)(row0 + r)*128 + 64 + o] = lsl[o];
  }
}

// ---------------- phase 1: per-chunk zero-init scan -> deltas D[ci][b][s]
__global__ __launch_bounds__(256) void k_phase1(const unsigned short* __restrict__ cuy,
                                                const float* __restrict__ Mt132g,
                                                float* __restrict__ Dd){
  __shared__ float mt[128*132];
  __shared__ float xl[32*128];
  int tid = threadIdx.x;
  int ci = blockIdx.x >> 2, bi = blockIdx.x & 3;
  int b0 = bi * 32, t0 = ci * K_CH;
  for (int li = tid*4; li < 128*132; li += 1024)
    *(float4*)&mt[li] = *(const float4*)&Mt132g[li];
  for (int li = tid; li < 32*128; li += 256) xl[li] = 0.f;
  int r0 = (tid >> 5) << 2, cb = tid & 31;
  unsigned short cn[4][4];
  #pragma unroll
  for (int i = 0; i < 4; ++i){
    size_t rowb = ((size_t)(b0 + r0 + i) * T_ + t0);
    #pragma unroll
    for (int j = 0; j < 4; ++j) cn[i][j] = cuy[rowb*192 + cb + 32*j];
  }
  __syncthreads();
  for (int s = 0; s < K_CH; ++s){
    float ax[4][4];
    #pragma unroll
    for (int i = 0; i < 4; ++i)
      #pragma unroll
      for (int j = 0; j < 4; ++j) ax[i][j] = bf2f(cn[i][j]);
    if (s + 1 < K_CH){
      #pragma unroll
      for (int i = 0; i < 4; ++i){
        size_t rowb = ((size_t)(b0 + r0 + i) * T_ + (t0 + s + 1));
        #pragma unroll
        for (int j = 0; j < 4; ++j) cn[i][j] = cuy[rowb*192 + cb + 32*j];
      }
    }
    #pragma unroll 4
    for (int kk = 0; kk < 128; kk += 4){
      float4 m0 = *(const float4*)&mt[(cb     )*132 + kk];
      float4 m1 = *(const float4*)&mt[(cb + 32)*132 + kk];
      float4 m2 = *(const float4*)&mt[(cb + 64)*132 + kk];
      float4 m3 = *(const float4*)&mt[(cb + 96)*132 + kk];
      #pragma unroll
      for (int i = 0; i < 4; ++i){
        float4 xv = *(const float4*)&xl[(r0+i)*128 + kk];
        ax[i][0] += xv.x*m0.x + xv.y*m0.y + xv.z*m0.z + xv.w*m0.w;
        ax[i][1] += xv.x*m1.x + xv.y*m1.y + xv.z*m1.z + xv.w*m1.w;
        ax[i][2] += xv.x*m2.x + xv.y*m2.y + xv.z*m2.z + xv.w*m2.w;
        ax[i][3] += xv.x*m3.x + xv.y*m3.y + xv.z*m3.z + xv.w*m3.w;
      }
    }
    __syncthreads();
    if (s + 1 == K_CH){
      #pragma unroll
      for (int i = 0; i < 4; ++i)
        #pragma unroll
        for (int j = 0; j < 4; ++j)
          Dd[(size_t)ci*16384 + (size_t)(b0 + r0 + i)*128 + cb + 32*j] = ax[i][j];
    } else {
      #pragma unroll
      for (int i = 0; i < 4; ++i){
        xl[(r0+i)*128 + cb     ] = ax[i][0];
        xl[(r0+i)*128 + cb + 32] = ax[i][1];
        xl[(r0+i)*128 + cb + 64] = ax[i][2];
        xl[(r0+i)*128 + cb + 96] = ax[i][3];
      }
      __syncthreads();
    }
  }
}

// ---------------- combine: sequential over 64 chunks, parallel over batch rows
__global__ __launch_bounds__(256) void k_combine(const float* __restrict__ Mk,
                                                 const float* __restrict__ Dd,
                                                 const float* __restrict__ x0,
                                                 float* __restrict__ XS,
                                                 float* __restrict__ xfin){
  __shared__ float xl[128];
  __shared__ float pl[256];
  int tid = threadIdx.x;
  int b = blockIdx.x;
  int c = tid & 127, h = tid >> 7;
  float mreg[64];
  #pragma unroll
  for (int j = 0; j < 64; ++j) mreg[j] = Mk[(64*h + j)*128 + c];
  if (tid < 128) xl[tid] = x0[(size_t)b*128 + tid];
  __syncthreads();
  for (int i = 0; i < C_CH; ++i){
    if (tid < 128) XS[(size_t)i*16384 + (size_t)b*128 + tid] = xl[tid];
    float part = 0.f;
    #pragma unroll
    for (int jj = 0; jj < 64; jj += 4){
      float4 xv = *(const float4*)&xl[64*h + jj];
      part += xv.x*mreg[jj] + xv.y*mreg[jj+1] + xv.z*mreg[jj+2] + xv.w*mreg[jj+3];
    }
    pl[tid] = part;
    __syncthreads();
    if (tid < 128)
      xl[tid] = pl[tid] + pl[tid + 128] + Dd[(size_t)i*16384 + (size_t)b*128 + tid];
    __syncthreads();
  }
  if (tid < 128) xfin[(size_t)b*128 + tid] = xl[tid];
}

// ---------------- phase 3: replay with true inits, fused action output
__global__ __launch_bounds__(256) void k_phase3(const unsigned short* __restrict__ cuy,
                                                const float* __restrict__ Mt132g,
                                                const float* __restrict__ Cut132g,
                                                const float* __restrict__ XS,
                                                float* __restrict__ out){
  __shared__ float mt[128*132];
  __shared__ float cut[64*132];
  __shared__ float xl[32*128];
  int tid = threadIdx.x;
  int ci = blockIdx.x >> 2, bi = blockIdx.x & 3;
  int b0 = bi * 32, t0 = ci * K_CH;
  for (int li = tid*4; li < 128*132; li += 1024)
    *(float4*)&mt[li] = *(const float4*)&Mt132g[li];
  for (int li = tid*4; li < 64*132; li += 1024)
    *(float4*)&cut[li] = *(const float4*)&Cut132g[li];
  for (int li = tid; li < 32*128; li += 256){
    int r = li >> 7, c2 = li & 127;
    xl[li] = XS[(size_t)ci*16384 + (size_t)(b0 + r)*128 + c2];
  }
  int r0 = (tid >> 5) << 2, cb = tid & 31;
  unsigned short cn[4][4], un[4][2];
  #pragma unroll
  for (int i = 0; i < 4; ++i){
    size_t rowb = ((size_t)(b0 + r0 + i) * T_ + t0);
    #pragma unroll
    for (int j = 0; j < 4; ++j) cn[i][j] = cuy[rowb*192 + cb + 32*j];
    un[i][0] = cuy[rowb*192 + 128 + cb];
    un[i][1] = cuy[rowb*192 + 128 + cb + 32];
  }
  __syncthreads();
  for (int s = 0; s < K_CH; ++s){
    float ax[4][4], au[4][2];
    #pragma unroll
    for (int i = 0; i < 4; ++i){
      #pragma unroll
      for (int j = 0; j < 4; ++j) ax[i][j] = bf2f(cn[i][j]);
      au[i][0] = bf2f(un[i][0]);
      au[i][1] = bf2f(un[i][1]);
    }
    if (s + 1 < K_CH){
      #pragma unroll
      for (int i = 0; i < 4; ++i){
        size_t rowb = ((size_t)(b0 + r0 + i) * T_ + (t0 + s + 1));
        #pragma unroll
        for (int j = 0; j < 4; ++j) cn[i][j] = cuy[rowb*192 + cb + 32*j];
        un[i][0] = cuy[rowb*192 + 128 + cb];
        un[i][1] = cuy[rowb*192 + 128 + cb + 32];
      }
    }
    #pragma unroll 2
    for (int kk = 0; kk < 128; kk += 4){
      float4 m0 = *(const float4*)&mt[(cb     )*132 + kk];
      float4 m1 = *(const float4*)&mt[(cb + 32)*132 + kk];
      float4 m2 = *(const float4*)&mt[(cb + 64)*132 + kk];
      float4 m3 = *(const float4*)&mt[(cb + 96)*132 + kk];
      float4 c0 = *(const float4*)&cut[(cb     )*132 + kk];
      float4 c1 = *(const float4*)&cut[(cb + 32)*132 + kk];
      #pragma unroll
      for (int i = 0; i < 4; ++i){
        float4 xv = *(const float4*)&xl[(r0+i)*128 + kk];
        ax[i][0] += xv.x*m0.x + xv.y*m0.y + xv.z*m0.z + xv.w*m0.w;
        ax[i][1] += xv.x*m1.x + xv.y*m1.y + xv.z*m1.z + xv.w*m1.w;
        ax[i][2] += xv.x*m2.x + xv.y*m2.y + xv.z*m2.z + xv.w*m2.w;
        ax[i][3] += xv.x*m3.x + xv.y*m3.y + xv.z*m3.z + xv.w*m3.w;
        au[i][0] += xv.x*c0.x + xv.y*c0.y + xv.z*c0.z + xv.w*c0.w;
        au[i][1] += xv.x*c1.x + xv.y*c1.y + xv.z*c1.z + xv.w*c1.w;
      }
    }
    int t = t0 + s;
    #pragma unroll
    for (int i = 0; i < 4; ++i){
      size_t ro = ((size_t)(b0 + r0 + i) * T_ + t) * 128;
      out[ro + cb]      = au[i][0];
      out[ro + cb + 32] = au[i][1];
    }
    __syncthreads();
    if (s + 1 < K_CH){
      #pragma unroll
      for (int i = 0; i < 4; ++i){
        xl[(r0+i)*128 + cb     ] = ax[i][0];
        xl[(r0+i)*128 + cb + 32] = ax[i][1];
        xl[(r0+i)*128 + cb + 64] = ax[i][2];
        xl[(r0+i)*128 + cb + 96] = ax[i][3];
      }
      __syncthreads();
    }
  }
}

extern "C" void kernel_launch(void* const* d_in, const int* in_sizes, int n_in,
                              void* d_out, int out_size, void* d_ws, size_t ws_size,
                              hipStream_t stream){
  const float* obs  = (const float*)d_in[0];
  const float* x0   = (const float*)d_in[1];
  const float* A_T  = (const float*)d_in[2];
  const float* By_T = (const float*)d_in[3];
  const float* Cu_T = (const float*)d_in[4];
  const float* Duy_T= (const float*)d_in[5];
  const float* ls   = (const float*)d_in[6];
  const float* W0   = (const float*)d_in[7];
  const float* b0   = (const float*)d_in[8];
  const float* W1   = (const float*)d_in[9];
  const float* b1   = (const float*)d_in[10];
  const float* W2   = (const float*)d_in[11];
  const float* b2   = (const float*)d_in[12];
  const float* dt   = (const float*)d_in[13];
  float* out = (float*)d_out;

  char* ws = (char*)d_ws;
  unsigned short* cuy = (unsigned short*)(ws + 0);            // 100663296 B
  float* A2     = (float*)(ws + 100663296);                   // 65536 each
  float* A3     = (float*)(ws + 100728832);
  float* A4     = (float*)(ws + 100794368);
  float* Mm     = (float*)(ws + 100859904);
  float* Pp     = (float*)(ws + 100925440);
  float* Mk     = (float*)(ws + 100990976);
  float* sq1    = (float*)(ws + 101056512);
  float* sq2    = (float*)(ws + 101122048);
  float* Mt132  = (float*)(ws + 101187584);                   // 67584 B
  float* Wcat   = (float*)(ws + 101255168);                   // 98304 B
  float* Cut132 = (float*)(ws + 101353472);                   // 33792 B
  float* Dd     = (float*)(ws + 101387264);                   // 4194304 B
  float* XS     = (float*)(ws + 105581568);                   // 4194304 B
  unsigned short* Wbf = (unsigned short*)Pp;                  // reuse Pp after G computed (49152 B)

  // ---- small setup chain
  k_mm<<<64, 256, 0, stream>>>(A_T, A_T, A2, 128);
  k_mm<<<64, 256, 0, stream>>>(A2, A_T, A3, 128);
  k_mm<<<64, 256, 0, stream>>>(A2, A2, A4, 128);
  k_build<<<64, 256, 0, stream>>>(A_T, A2, A3, A4, Cu_T, Duy_T, dt, Mm, Mt132, Pp, Wcat, Cut132);
  k_mm<<<64, 256, 0, stream>>>(By_T, Pp, Wcat, 192);          // G -> Wcat cols 0..127
  k_cvtw<<<96, 256, 0, stream>>>(Wcat, Wbf);                  // Wcat -> bf16 (Pp dead now)
  k_mm<<<64, 256, 0, stream>>>(Mm, Mm, sq1, 128);             // M^2
  k_mm<<<64, 256, 0, stream>>>(sq1, sq1, sq2, 128);           // M^4
  k_mm<<<64, 256, 0, stream>>>(sq2, sq2, sq1, 128);           // M^8
  k_mm<<<64, 256, 0, stream>>>(sq1, sq1, sq2, 128);           // M^16
  k_mm<<<64, 256, 0, stream>>>(sq2, sq2, Mk, 128);            // M^32

  // ---- big parallel work
  k_b1<<<NR/128, 256, 0, stream>>>(obs, Wbf, cuy);
  k_phase1<<<C_CH*4, 256, 0, stream>>>(cuy, Mt132, Dd);
  k_combine<<<B_, 256, 0, stream>>>(Mk, Dd, x0, XS, out + XFOFF);
  k_phase3<<<C_CH*4, 256, 0, stream>>>(cuy, Mt132, Cut132, XS, out);
  k_b2<<<NR/64, 256, 0, stream>>>(obs, W0, b0, W1, b1, W2, b2, ls, out);
}

// Round 4
// 557.512 us; speedup vs baseline: 2.1520x; 1.7792x over previous
//
#include <hip/hip_runtime.h>

#define B_    128
#define T_    2048
#define OBS_  128
#define S_    128
#define OUT_  64
#define H_    64
#define NR    (B_*T_)            // 262144 rows
#define K_CH  32                 // chunk length
#define C_CH  64                 // number of chunks
#define VOFF  (NR*2*OUT_)        // 33554432 : cur_value offset in d_out
#define XFOFF (VOFF + NR)        // 33816576 : x_final offset in d_out

typedef __attribute__((ext_vector_type(8))) short short8v;   // 8 bf16 (4 VGPRs)
typedef __attribute__((ext_vector_type(4))) float f32x4;

__device__ __forceinline__ unsigned short f2bf(float f){
  unsigned int u = __float_as_uint(f);
  u += 0x7FFFu + ((u >> 16) & 1u);
  return (unsigned short)(u >> 16);
}
__device__ __forceinline__ float bf2f(unsigned short h){
  return __uint_as_float(((unsigned int)h) << 16);
}

// ---------------- generic 128x128 @ 128x128 matmul: C[r*ldc+c] = sum_k A[r][k]B[k][c]
__global__ __launch_bounds__(256) void k_mm(const float* __restrict__ A,
                                            const float* __restrict__ B,
                                            float* __restrict__ C, int ldc){
  int e = blockIdx.x * 256 + threadIdx.x;     // 16384 output elems
  int r = e >> 7, c = e & 127;
  float acc = 0.f;
  #pragma unroll 4
  for (int k = 0; k < 128; ++k) acc += A[r*128 + k] * B[k*128 + c];
  C[r*ldc + c] = acc;
}

// ---------------- build M, Mmi(bf16), P, Duy->Wcat, Cu->bf16
__global__ __launch_bounds__(256) void k_build(const float* __restrict__ A_T,
                                               const float* __restrict__ A2,
                                               const float* __restrict__ A3,
                                               const float* __restrict__ A4,
                                               const float* __restrict__ Cu_T,
                                               const float* __restrict__ Duy_T,
                                               const float* __restrict__ dtp,
                                               float* __restrict__ M,
                                               unsigned short* __restrict__ Mmibf,
                                               float* __restrict__ P, float* __restrict__ Wcat,
                                               unsigned short* __restrict__ cubf){
  float dt = *dtp;
  float d2 = dt*dt*0.5f;
  float d3 = d2*dt*(1.f/3.f);
  float d4 = d3*dt*0.25f;
  int e = blockIdx.x * 256 + threadIdx.x;     // 0..16383
  int r = e >> 7, c = e & 127;
  float eye = (r == c) ? 1.f : 0.f;
  float mi = dt*A_T[e] + d2*A2[e] + d3*A3[e] + d4*A4[e];   // M - I (small entries)
  M[e] = eye + mi;
  Mmibf[e] = f2bf(mi);
  P[e] = dt*eye + d2*A_T[e] + d3*A2[e] + d4*A3[e];
  if (e < 128*64){
    int k = e >> 6, o = e & 63;
    Wcat[k*192 + 128 + o] = Duy_T[e];         // Duy columns of Wcat
    cubf[e] = f2bf(Cu_T[e]);                  // Cu bf16 [k][out]
  }
}

// ---------------- convert Wcat f32 [128,192] -> bf16
__global__ __launch_bounds__(256) void k_cvtw(const float* __restrict__ Wcat,
                                              unsigned short* __restrict__ Wbf){
  int e = blockIdx.x * 256 + threadIdx.x;     // 0..24575
  Wbf[e] = f2bf(Wcat[e]);
}

// ---------------- B1 (MFMA): cuy[NR,192] = bf16( obs[NR,128] @ Wbf[128,192] )
__global__ __launch_bounds__(256) void k_b1(const float* __restrict__ obs,
                                            const unsigned short* __restrict__ Wbf,
                                            unsigned short* __restrict__ cuy){
  __shared__ __align__(16) unsigned short ct[128*200];  // 50 KiB repack tile (pad 192->200)
  int tid = threadIdx.x;
  int lane = tid & 63, w = tid >> 6;
  size_t row0 = (size_t)blockIdx.x * 128;
  int colbase = w * 48;
  int lr = lane & 15;                         // A row / B,D col within frag
  int lk = (lane >> 4) * 8;                   // K offset within frag

  short8v bfrag[3][4];
  #pragma unroll
  for (int cf = 0; cf < 3; ++cf)
    #pragma unroll
    for (int kk = 0; kk < 4; ++kk){
      short8v b;
      #pragma unroll
      for (int j = 0; j < 8; ++j)
        b[j] = (short)Wbf[(size_t)(kk*32 + lk + j)*192 + (colbase + cf*16 + lr)];
      bfrag[cf][kk] = b;
    }

  for (int rf = 0; rf < 8; ++rf){
    f32x4 acc0 = {0.f,0.f,0.f,0.f}, acc1 = {0.f,0.f,0.f,0.f}, acc2 = {0.f,0.f,0.f,0.f};
    const float* arow = obs + (row0 + (size_t)(rf*16 + lr)) * 128;
    #pragma unroll
    for (int kk = 0; kk < 4; ++kk){
      float4 a0 = *(const float4*)&arow[kk*32 + lk];
      float4 a1 = *(const float4*)&arow[kk*32 + lk + 4];
      short8v af;
      af[0] = (short)f2bf(a0.x); af[1] = (short)f2bf(a0.y);
      af[2] = (short)f2bf(a0.z); af[3] = (short)f2bf(a0.w);
      af[4] = (short)f2bf(a1.x); af[5] = (short)f2bf(a1.y);
      af[6] = (short)f2bf(a1.z); af[7] = (short)f2bf(a1.w);
      acc0 = __builtin_amdgcn_mfma_f32_16x16x32_bf16(af, bfrag[0][kk], acc0, 0, 0, 0);
      acc1 = __builtin_amdgcn_mfma_f32_16x16x32_bf16(af, bfrag[1][kk], acc1, 0, 0, 0);
      acc2 = __builtin_amdgcn_mfma_f32_16x16x32_bf16(af, bfrag[2][kk], acc2, 0, 0, 0);
    }
    int orow = rf*16 + (lane >> 4)*4;         // D: col=lane&15, row=(lane>>4)*4+j
    #pragma unroll
    for (int j = 0; j < 4; ++j){
      ct[(orow + j)*200 + colbase      + lr] = f2bf(acc0[j]);
      ct[(orow + j)*200 + colbase + 16 + lr] = f2bf(acc1[j]);
      ct[(orow + j)*200 + colbase + 32 + lr] = f2bf(acc2[j]);
    }
  }
  __syncthreads();
  for (int li = tid; li < 128*24; li += 256){
    int r = li / 24, seg = li % 24;
    *(uint4*)&cuy[(row0 + r)*192 + seg*8] = *(const uint4*)&ct[r*200 + seg*8];
  }
}

// ---------------- B2: value MLP + log_stds broadcast
__global__ __launch_bounds__(256) void k_b2(const float* __restrict__ obs,
                                            const float* __restrict__ W0, const float* __restrict__ b0,
                                            const float* __restrict__ W1, const float* __restrict__ b1,
                                            const float* __restrict__ W2, const float* __restrict__ b2,
                                            const float* __restrict__ ls, float* __restrict__ out){
  __shared__ float ylds[64*132];
  __shared__ float w0l[64*132];
  __shared__ float h0l[64*68];
  __shared__ float w1l[64*68];
  __shared__ float h1l[64*68];
  __shared__ float w2l[64];
  __shared__ float b0l[64], b1l[64], lsl[64];
  int tid = threadIdx.x;
  int row0 = blockIdx.x * 64;
  for (int li = tid*4; li < 64*128; li += 1024){
    int r = li >> 7, k = li & 127;
    *(float4*)&ylds[r*132 + k] = *(const float4*)&obs[(size_t)(row0 + r)*128 + k];
    *(float4*)&w0l [r*132 + k] = *(const float4*)&W0[li];
  }
  for (int li = tid*4; li < 64*64; li += 1024){
    int r = li >> 6, k = li & 63;
    *(float4*)&w1l[r*68 + k] = *(const float4*)&W1[li];
  }
  if (tid < 64){ w2l[tid] = W2[tid]; b0l[tid] = b0[tid]; b1l[tid] = b1[tid]; lsl[tid] = ls[tid]; }
  __syncthreads();
  int r0 = (tid >> 4) << 2, hb = tid & 15;
  { // layer 0
    float acc[4][4] = {};
    #pragma unroll 4
    for (int kk = 0; kk < 128; kk += 4){
      float4 wa = *(const float4*)&w0l[(hb     )*132 + kk];
      float4 wb = *(const float4*)&w0l[(hb + 16)*132 + kk];
      float4 wc = *(const float4*)&w0l[(hb + 32)*132 + kk];
      float4 wd = *(const float4*)&w0l[(hb + 48)*132 + kk];
      #pragma unroll
      for (int i = 0; i < 4; ++i){
        float4 yv = *(const float4*)&ylds[(r0+i)*132 + kk];
        acc[i][0] += yv.x*wa.x + yv.y*wa.y + yv.z*wa.z + yv.w*wa.w;
        acc[i][1] += yv.x*wb.x + yv.y*wb.y + yv.z*wb.z + yv.w*wb.w;
        acc[i][2] += yv.x*wc.x + yv.y*wc.y + yv.z*wc.z + yv.w*wc.w;
        acc[i][3] += yv.x*wd.x + yv.y*wd.y + yv.z*wd.z + yv.w*wd.w;
      }
    }
    #pragma unroll
    for (int i = 0; i < 4; ++i){
      #pragma unroll
      for (int j = 0; j < 4; ++j)
        h0l[(r0+i)*68 + hb + 16*j] = tanhf(acc[i][j] + b0l[hb + 16*j]);
    }
  }
  __syncthreads();
  { // layer 1
    float acc[4][4] = {};
    #pragma unroll 4
    for (int kk = 0; kk < 64; kk += 4){
      float4 wa = *(const float4*)&w1l[(hb     )*68 + kk];
      float4 wb = *(const float4*)&w1l[(hb + 16)*68 + kk];
      float4 wc = *(const float4*)&w1l[(hb + 32)*68 + kk];
      float4 wd = *(const float4*)&w1l[(hb + 48)*68 + kk];
      #pragma unroll
      for (int i = 0; i < 4; ++i){
        float4 hv = *(const float4*)&h0l[(r0+i)*68 + kk];
        acc[i][0] += hv.x*wa.x + hv.y*wa.y + hv.z*wa.z + hv.w*wa.w;
        acc[i][1] += hv.x*wb.x + hv.y*wb.y + hv.z*wb.z + hv.w*wb.w;
        acc[i][2] += hv.x*wc.x + hv.y*wc.y + hv.z*wc.z + hv.w*wc.w;
        acc[i][3] += hv.x*wd.x + hv.y*wd.y + hv.z*wd.z + hv.w*wd.w;
      }
    }
    #pragma unroll
    for (int i = 0; i < 4; ++i){
      #pragma unroll
      for (int j = 0; j < 4; ++j)
        h1l[(r0+i)*68 + hb + 16*j] = tanhf(acc[i][j] + b1l[hb + 16*j]);
    }
  }
  __syncthreads();
  if (tid < 64){ // value head
    float acc = b2[0];
    #pragma unroll
    for (int kk = 0; kk < 64; kk += 4){
      float4 hv = *(const float4*)&h1l[tid*68 + kk];
      float4 wv = *(const float4*)&w2l[kk];
      acc += hv.x*wv.x + hv.y*wv.y + hv.z*wv.z + hv.w*wv.w;
    }
    out[(size_t)VOFF + row0 + tid] = acc;
  }
  for (int li = tid; li < 64*64; li += 256){
    int r = li >> 6, o = li & 63;
    out[(size_t)(row0 + r)*128 + 64 + o] = lsl[o];
  }
}

// ---------------- phase 1 (MFMA): per-chunk zero-init scan -> deltas D[ci][b][s]
// x kept in f32 MFMA accumulators; bf16 only on the delta path x@(M-I).
// Two barriers per step: write -> bar -> read -> bar (provably race-free).
__global__ __launch_bounds__(256) void k_phase1(const unsigned short* __restrict__ cuy,
                                                const unsigned short* __restrict__ Mmibf,
                                                float* __restrict__ Dd){
  __shared__ __align__(16) unsigned short xw[32*136];
  int tid = threadIdx.x;
  int lane = tid & 63, w = tid >> 6;
  int lr = lane & 15, lg = lane >> 4;
  int ci = blockIdx.x >> 2, bi = blockIdx.x & 3;
  int b0 = bi*32, t0 = ci*K_CH;
  int colbase = w*32;

  short8v bm[2][4];                            // M-I columns, resident
  #pragma unroll
  for (int ctt = 0; ctt < 2; ++ctt)
    #pragma unroll
    for (int kk = 0; kk < 4; ++kk){
      short8v b;
      #pragma unroll
      for (int j = 0; j < 8; ++j)
        b[j] = (short)Mmibf[(size_t)(kk*32 + lg*8 + j)*128 + colbase + ctt*16 + lr];
      bm[ctt][kk] = b;
    }

  f32x4 acc[2][2];                             // x_1 = c_{t0}
  #pragma unroll
  for (int rt = 0; rt < 2; ++rt)
    #pragma unroll
    for (int ctt = 0; ctt < 2; ++ctt)
      #pragma unroll
      for (int j = 0; j < 4; ++j)
        acc[rt][ctt][j] = bf2f(cuy[((size_t)(b0 + rt*16 + lg*4 + j)*T_ + t0)*192 + colbase + ctt*16 + lr]);

  for (int s = 1; s < K_CH; ++s){
    unsigned short cn[2][2][4];
    #pragma unroll
    for (int rt = 0; rt < 2; ++rt)
      #pragma unroll
      for (int ctt = 0; ctt < 2; ++ctt)
        #pragma unroll
        for (int j = 0; j < 4; ++j)
          cn[rt][ctt][j] = cuy[((size_t)(b0 + rt*16 + lg*4 + j)*T_ + t0 + s)*192 + colbase + ctt*16 + lr];
    #pragma unroll
    for (int rt = 0; rt < 2; ++rt)
      #pragma unroll
      for (int ctt = 0; ctt < 2; ++ctt)
        #pragma unroll
        for (int j = 0; j < 4; ++j)
          xw[(rt*16 + lg*4 + j)*136 + colbase + ctt*16 + lr] = f2bf(acc[rt][ctt][j]);
    __syncthreads();
    short8v af[2][4];
    #pragma unroll
    for (int rt = 0; rt < 2; ++rt)
      #pragma unroll
      for (int kk = 0; kk < 4; ++kk)
        af[rt][kk] = *(const short8v*)&xw[(rt*16 + lr)*136 + kk*32 + lg*8];
    __syncthreads();
    #pragma unroll
    for (int rt = 0; rt < 2; ++rt)
      #pragma unroll
      for (int ctt = 0; ctt < 2; ++ctt)
        #pragma unroll
        for (int kk = 0; kk < 4; ++kk)
          acc[rt][ctt] = __builtin_amdgcn_mfma_f32_16x16x32_bf16(af[rt][kk], bm[ctt][kk], acc[rt][ctt], 0, 0, 0);
    #pragma unroll
    for (int rt = 0; rt < 2; ++rt)
      #pragma unroll
      for (int ctt = 0; ctt < 2; ++ctt)
        #pragma unroll
        for (int j = 0; j < 4; ++j)
          acc[rt][ctt][j] += bf2f(cn[rt][ctt][j]);
  }
  #pragma unroll
  for (int rt = 0; rt < 2; ++rt)
    #pragma unroll
    for (int ctt = 0; ctt < 2; ++ctt)
      #pragma unroll
      for (int j = 0; j < 4; ++j)
        Dd[(size_t)ci*16384 + (size_t)(b0 + rt*16 + lg*4 + j)*128 + colbase + ctt*16 + lr] = acc[rt][ctt][j];
}

// ---------------- combine: sequential over 64 chunks, parallel over batch rows
__global__ __launch_bounds__(256) void k_combine(const float* __restrict__ Mk,
                                                 const float* __restrict__ Dd,
                                                 const float* __restrict__ x0,
                                                 float* __restrict__ XS,
                                                 float* __restrict__ xfin){
  __shared__ float xl[128];
  __shared__ float pl[256];
  int tid = threadIdx.x;
  int b = blockIdx.x;
  int c = tid & 127, h = tid >> 7;
  float mreg[64];
  #pragma unroll
  for (int j = 0; j < 64; ++j) mreg[j] = Mk[(64*h + j)*128 + c];
  if (tid < 128) xl[tid] = x0[(size_t)b*128 + tid];
  __syncthreads();
  for (int i = 0; i < C_CH; ++i){
    if (tid < 128) XS[(size_t)i*16384 + (size_t)b*128 + tid] = xl[tid];
    float part = 0.f;
    #pragma unroll
    for (int jj = 0; jj < 64; jj += 4){
      float4 xv = *(const float4*)&xl[64*h + jj];
      part += xv.x*mreg[jj] + xv.y*mreg[jj+1] + xv.z*mreg[jj+2] + xv.w*mreg[jj+3];
    }
    pl[tid] = part;
    __syncthreads();
    if (tid < 128)
      xl[tid] = pl[tid] + pl[tid + 128] + Dd[(size_t)i*16384 + (size_t)b*128 + tid];
    __syncthreads();
  }
  if (tid < 128) xfin[(size_t)b*128 + tid] = xl[tid];
}

// ---------------- phase 3 (MFMA): replay with true inits, fused action output
__global__ __launch_bounds__(256) void k_phase3(const unsigned short* __restrict__ cuy,
                                                const unsigned short* __restrict__ Mmibf,
                                                const unsigned short* __restrict__ cubf,
                                                const float* __restrict__ XS,
                                                float* __restrict__ out){
  __shared__ __align__(16) unsigned short xw[32*136];
  int tid = threadIdx.x;
  int lane = tid & 63, w = tid >> 6;
  int lr = lane & 15, lg = lane >> 4;
  int ci = blockIdx.x >> 2, bi = blockIdx.x & 3;
  int b0 = bi*32, t0 = ci*K_CH;
  int colbase = w*32;
  int ucolbase = w*16;

  short8v bm[2][4];
  #pragma unroll
  for (int ctt = 0; ctt < 2; ++ctt)
    #pragma unroll
    for (int kk = 0; kk < 4; ++kk){
      short8v b;
      #pragma unroll
      for (int j = 0; j < 8; ++j)
        b[j] = (short)Mmibf[(size_t)(kk*32 + lg*8 + j)*128 + colbase + ctt*16 + lr];
      bm[ctt][kk] = b;
    }
  short8v bc[4];                               // Cu columns, resident
  #pragma unroll
  for (int kk = 0; kk < 4; ++kk){
    short8v b;
    #pragma unroll
    for (int j = 0; j < 8; ++j)
      b[j] = (short)cubf[(size_t)(kk*32 + lg*8 + j)*64 + ucolbase + lr];
    bc[kk] = b;
  }

  f32x4 acc[2][2];                             // x_{t0} from combine (f32)
  #pragma unroll
  for (int rt = 0; rt < 2; ++rt)
    #pragma unroll
    for (int ctt = 0; ctt < 2; ++ctt)
      #pragma unroll
      for (int j = 0; j < 4; ++j)
        acc[rt][ctt][j] = XS[(size_t)ci*16384 + (size_t)(b0 + rt*16 + lg*4 + j)*128 + colbase + ctt*16 + lr];

  for (int s = 0; s < K_CH; ++s){
    f32x4 au[2];                               // u = uy + x@Cu
    #pragma unroll
    for (int rt = 0; rt < 2; ++rt)
      #pragma unroll
      for (int j = 0; j < 4; ++j)
        au[rt][j] = bf2f(cuy[((size_t)(b0 + rt*16 + lg*4 + j)*T_ + t0 + s)*192 + 128 + ucolbase + lr]);
    unsigned short cn[2][2][4];
    if (s + 1 < K_CH){
      #pragma unroll
      for (int rt = 0; rt < 2; ++rt)
        #pragma unroll
        for (int ctt = 0; ctt < 2; ++ctt)
          #pragma unroll
          for (int j = 0; j < 4; ++j)
            cn[rt][ctt][j] = cuy[((size_t)(b0 + rt*16 + lg*4 + j)*T_ + t0 + s)*192 + colbase + ctt*16 + lr];
    }
    #pragma unroll
    for (int rt = 0; rt < 2; ++rt)
      #pragma unroll
      for (int ctt = 0; ctt < 2; ++ctt)
        #pragma unroll
        for (int j = 0; j < 4; ++j)
          xw[(rt*16 + lg*4 + j)*136 + colbase + ctt*16 + lr] = f2bf(acc[rt][ctt][j]);
    __syncthreads();
    short8v af[2][4];
    #pragma unroll
    for (int rt = 0; rt < 2; ++rt)
      #pragma unroll
      for (int kk = 0; kk < 4; ++kk)
        af[rt][kk] = *(const short8v*)&xw[(rt*16 + lr)*136 + kk*32 + lg*8];
    __syncthreads();
    // u output
    #pragma unroll
    for (int rt = 0; rt < 2; ++rt)
      #pragma unroll
      for (int kk = 0; kk < 4; ++kk)
        au[rt] = __builtin_amdgcn_mfma_f32_16x16x32_bf16(af[rt][kk], bc[kk], au[rt], 0, 0, 0);
    #pragma unroll
    for (int rt = 0; rt < 2; ++rt)
      #pragma unroll
      for (int j = 0; j < 4; ++j)
        out[((size_t)(b0 + rt*16 + lg*4 + j)*T_ + t0 + s)*128 + ucolbase + lr] = au[rt][j];
    // x update (skip on last step)
    if (s + 1 < K_CH){
      #pragma unroll
      for (int rt = 0; rt < 2; ++rt)
        #pragma unroll
        for (int ctt = 0; ctt < 2; ++ctt)
          #pragma unroll
          for (int kk = 0; kk < 4; ++kk)
            acc[rt][ctt] = __builtin_amdgcn_mfma_f32_16x16x32_bf16(af[rt][kk], bm[ctt][kk], acc[rt][ctt], 0, 0, 0);
      #pragma unroll
      for (int rt = 0; rt < 2; ++rt)
        #pragma unroll
        for (int ctt = 0; ctt < 2; ++ctt)
          #pragma unroll
          for (int j = 0; j < 4; ++j)
            acc[rt][ctt][j] += bf2f(cn[rt][ctt][j]);
    }
  }
}

extern "C" void kernel_launch(void* const* d_in, const int* in_sizes, int n_in,
                              void* d_out, int out_size, void* d_ws, size_t ws_size,
                              hipStream_t stream){
  const float* obs  = (const float*)d_in[0];
  const float* x0   = (const float*)d_in[1];
  const float* A_T  = (const float*)d_in[2];
  const float* By_T = (const float*)d_in[3];
  const float* Cu_T = (const float*)d_in[4];
  const float* Duy_T= (const float*)d_in[5];
  const float* ls   = (const float*)d_in[6];
  const float* W0   = (const float*)d_in[7];
  const float* b0   = (const float*)d_in[8];
  const float* W1   = (const float*)d_in[9];
  const float* b1   = (const float*)d_in[10];
  const float* W2   = (const float*)d_in[11];
  const float* b2   = (const float*)d_in[12];
  const float* dt   = (const float*)d_in[13];
  float* out = (float*)d_out;

  char* ws = (char*)d_ws;
  unsigned short* cuy = (unsigned short*)(ws + 0);            // 100663296 B
  float* A2     = (float*)(ws + 100663296);                   // 65536 each
  float* A3     = (float*)(ws + 100728832);
  float* A4     = (float*)(ws + 100794368);
  float* Mm     = (float*)(ws + 100859904);
  float* Pp     = (float*)(ws + 100925440);
  float* Mk     = (float*)(ws + 100990976);
  float* sq1    = (float*)(ws + 101056512);
  float* sq2    = (float*)(ws + 101122048);
  unsigned short* Mmibf = (unsigned short*)(ws + 101187584);  // 32768 B
  float* Wcat   = (float*)(ws + 101255168);                   // 98304 B
  unsigned short* cubf  = (unsigned short*)(ws + 101353472);  // 16384 B
  float* Dd     = (float*)(ws + 101387264);                   // 4194304 B
  float* XS     = (float*)(ws + 105581568);                   // 4194304 B
  unsigned short* Wbf = (unsigned short*)Pp;                  // reuse Pp after G computed (49152 B)

  // ---- small setup chain
  k_mm<<<64, 256, 0, stream>>>(A_T, A_T, A2, 128);
  k_mm<<<64, 256, 0, stream>>>(A2, A_T, A3, 128);
  k_mm<<<64, 256, 0, stream>>>(A2, A2, A4, 128);
  k_build<<<64, 256, 0, stream>>>(A_T, A2, A3, A4, Cu_T, Duy_T, dt, Mm, Mmibf, Pp, Wcat, cubf);
  k_mm<<<64, 256, 0, stream>>>(By_T, Pp, Wcat, 192);          // G -> Wcat cols 0..127
  k_cvtw<<<96, 256, 0, stream>>>(Wcat, Wbf);                  // Wcat -> bf16 (Pp dead now)
  k_mm<<<64, 256, 0, stream>>>(Mm, Mm, sq1, 128);             // M^2
  k_mm<<<64, 256, 0, stream>>>(sq1, sq1, sq2, 128);           // M^4
  k_mm<<<64, 256, 0, stream>>>(sq2, sq2, sq1, 128);           // M^8
  k_mm<<<64, 256, 0, stream>>>(sq1, sq1, sq2, 128);           // M^16
  k_mm<<<64, 256, 0, stream>>>(sq2, sq2, Mk, 128);            // M^32

  // ---- big parallel work
  k_b1<<<NR/128, 256, 0, stream>>>(obs, Wbf, cuy);
  k_phase1<<<C_CH*4, 256, 0, stream>>>(cuy, Mmibf, Dd);
  k_combine<<<B_, 256, 0, stream>>>(Mk, Dd, x0, XS, out + XFOFF);
  k_phase3<<<C_CH*4, 256, 0, stream>>>(cuy, Mmibf, cubf, XS, out);
  k_b2<<<NR/64, 256, 0, stream>>>(obs, W0, b0, W1, b1, W2, b2, ls, out);
}

// Round 5
// 319.517 us; speedup vs baseline: 3.7549x; 1.7449x over previous
//
#include <hip/hip_runtime.h>

#define B_    128
#define T_    2048
#define OBS_  128
#define S_    128
#define OUT_  64
#define H_    64
#define NR    (B_*T_)            // 262144 rows
#define K_CH  32                 // chunk length
#define C_CH  64                 // number of chunks
#define VOFF  (NR*2*OUT_)        // 33554432 : cur_value offset in d_out
#define XFOFF (VOFF + NR)        // 33816576 : x_final offset in d_out

typedef __attribute__((ext_vector_type(8))) short short8v;   // 8 bf16 (4 VGPRs)
typedef __attribute__((ext_vector_type(4))) float f32x4;

__device__ __forceinline__ unsigned short f2bf(float f){
  unsigned int u = __float_as_uint(f);
  u += 0x7FFFu + ((u >> 16) & 1u);
  return (unsigned short)(u >> 16);
}
__device__ __forceinline__ float bf2f(unsigned short h){
  return __uint_as_float(((unsigned int)h) << 16);
}

// ---------------- generic 128x128 @ 128x128 matmul: C[r*ldc+c] = sum_k A[r][k]B[k][c]
__global__ __launch_bounds__(256) void k_mm(const float* __restrict__ A,
                                            const float* __restrict__ B,
                                            float* __restrict__ C, int ldc){
  int e = blockIdx.x * 256 + threadIdx.x;     // 16384 output elems
  int r = e >> 7, c = e & 127;
  float acc = 0.f;
  #pragma unroll 4
  for (int k = 0; k < 128; ++k) acc += A[r*128 + k] * B[k*128 + c];
  C[r*ldc + c] = acc;
}

// ---------------- build M, Mmi(bf16), P, Duy->Wcat, Cu->bf16
__global__ __launch_bounds__(256) void k_build(const float* __restrict__ A_T,
                                               const float* __restrict__ A2,
                                               const float* __restrict__ A3,
                                               const float* __restrict__ A4,
                                               const float* __restrict__ Cu_T,
                                               const float* __restrict__ Duy_T,
                                               const float* __restrict__ dtp,
                                               float* __restrict__ M,
                                               unsigned short* __restrict__ Mmibf,
                                               float* __restrict__ P, float* __restrict__ Wcat,
                                               unsigned short* __restrict__ cubf){
  float dt = *dtp;
  float d2 = dt*dt*0.5f;
  float d3 = d2*dt*(1.f/3.f);
  float d4 = d3*dt*0.25f;
  int e = blockIdx.x * 256 + threadIdx.x;     // 0..16383
  int r = e >> 7, c = e & 127;
  float eye = (r == c) ? 1.f : 0.f;
  float mi = dt*A_T[e] + d2*A2[e] + d3*A3[e] + d4*A4[e];   // M - I (small entries)
  M[e] = eye + mi;
  Mmibf[e] = f2bf(mi);
  P[e] = dt*eye + d2*A_T[e] + d3*A2[e] + d4*A3[e];
  if (e < 128*64){
    int k = e >> 6, o = e & 63;
    Wcat[k*192 + 128 + o] = Duy_T[e];         // Duy columns of Wcat
    cubf[e] = f2bf(Cu_T[e]);                  // Cu bf16 [k][out]
  }
}

// ---------------- convert Wcat/W0/W1 f32 -> bf16 (Wcat 24576, W0 8192, W1 4096)
__global__ __launch_bounds__(256) void k_cvtw(const float* __restrict__ Wcat,
                                              const float* __restrict__ W0,
                                              const float* __restrict__ W1,
                                              unsigned short* __restrict__ Wbf,
                                              unsigned short* __restrict__ W0bf,
                                              unsigned short* __restrict__ W1bf){
  int e = blockIdx.x * 256 + threadIdx.x;     // 0..36863
  if (e < 24576)       Wbf[e]          = f2bf(Wcat[e]);
  else if (e < 32768)  W0bf[e - 24576] = f2bf(W0[e - 24576]);
  else                 W1bf[e - 32768] = f2bf(W1[e - 32768]);
}

// ---------------- fused B1+B2 (MFMA): cuy = bf16(obs@Wcat), value MLP, log_stds
__global__ __launch_bounds__(256) void k_fused(const float* __restrict__ obs,
                                               const unsigned short* __restrict__ Wbf,
                                               const unsigned short* __restrict__ W0bf,
                                               const unsigned short* __restrict__ W1bf,
                                               const float* __restrict__ W2,
                                               const float* __restrict__ b0g,
                                               const float* __restrict__ b1g,
                                               const float* __restrict__ b2g,
                                               const float* __restrict__ ls,
                                               unsigned short* __restrict__ cuy,
                                               float* __restrict__ out){
  __shared__ __align__(16) unsigned short ct[128*200];   // 50 KiB cuy repack
  __shared__ __align__(16) unsigned short h0l[128*80];   // 20 KiB h0 (bf16)
  __shared__ float pl[128][4];                           // 2 KiB value partials
  int tid = threadIdx.x;
  int lane = tid & 63, w = tid >> 6;
  size_t row0 = (size_t)blockIdx.x * 128;
  int colbase = w * 48;                       // cuy cols (192/4 waves)
  int colh    = w * 16;                       // h cols (64/4 waves)
  int lr = lane & 15;                         // A row / B,D col within frag
  int lk = (lane >> 4) * 8;                   // K offset within frag

  // ---- resident B fragments
  short8v bfrag[3][4];                        // Wcat: 3 col-frags x 4 k-frags
  #pragma unroll
  for (int cf = 0; cf < 3; ++cf)
    #pragma unroll
    for (int kk = 0; kk < 4; ++kk){
      short8v b;
      #pragma unroll
      for (int j = 0; j < 8; ++j)
        b[j] = (short)Wbf[(size_t)(kk*32 + lk + j)*192 + (colbase + cf*16 + lr)];
      bfrag[cf][kk] = b;
    }
  short8v bw0[4];                             // W0^T: B[k][col] = W0bf[col*128+k]
  #pragma unroll
  for (int kk = 0; kk < 4; ++kk)
    bw0[kk] = *(const short8v*)&W0bf[(size_t)(colh + lr)*128 + kk*32 + lk];
  short8v bw1[2];                             // W1^T: B[k][col] = W1bf[col*64+k]
  #pragma unroll
  for (int kk = 0; kk < 2; ++kk)
    bw1[kk] = *(const short8v*)&W1bf[(size_t)(colh + lr)*64 + kk*32 + lk];
  float b0v = b0g[colh + lr];
  float b1v = b1g[colh + lr];
  float w2v = W2[colh + lr];

  // ---- phase A: big GEMM (cuy) + layer0
  for (int rf = 0; rf < 8; ++rf){
    f32x4 acc0 = {0.f,0.f,0.f,0.f}, acc1 = {0.f,0.f,0.f,0.f}, acc2 = {0.f,0.f,0.f,0.f};
    f32x4 acch = {0.f,0.f,0.f,0.f};
    const float* arow = obs + (row0 + (size_t)(rf*16 + lr)) * 128;
    #pragma unroll
    for (int kk = 0; kk < 4; ++kk){
      float4 a0 = *(const float4*)&arow[kk*32 + lk];
      float4 a1 = *(const float4*)&arow[kk*32 + lk + 4];
      short8v af;
      af[0] = (short)f2bf(a0.x); af[1] = (short)f2bf(a0.y);
      af[2] = (short)f2bf(a0.z); af[3] = (short)f2bf(a0.w);
      af[4] = (short)f2bf(a1.x); af[5] = (short)f2bf(a1.y);
      af[6] = (short)f2bf(a1.z); af[7] = (short)f2bf(a1.w);
      acc0 = __builtin_amdgcn_mfma_f32_16x16x32_bf16(af, bfrag[0][kk], acc0, 0, 0, 0);
      acc1 = __builtin_amdgcn_mfma_f32_16x16x32_bf16(af, bfrag[1][kk], acc1, 0, 0, 0);
      acc2 = __builtin_amdgcn_mfma_f32_16x16x32_bf16(af, bfrag[2][kk], acc2, 0, 0, 0);
      acch = __builtin_amdgcn_mfma_f32_16x16x32_bf16(af, bw0[kk],     acch, 0, 0, 0);
    }
    int orow = rf*16 + (lane >> 4)*4;         // D: col=lane&15, row=(lane>>4)*4+j
    #pragma unroll
    for (int j = 0; j < 4; ++j){
      ct[(orow + j)*200 + colbase      + lr] = f2bf(acc0[j]);
      ct[(orow + j)*200 + colbase + 16 + lr] = f2bf(acc1[j]);
      ct[(orow + j)*200 + colbase + 32 + lr] = f2bf(acc2[j]);
      h0l[(orow + j)*80 + colh + lr]         = f2bf(tanhf(acch[j] + b0v));
    }
  }
  __syncthreads();

  // ---- cuy store (coalesced 16B)
  for (int li = tid; li < 128*24; li += 256){
    int r = li / 24, seg = li % 24;
    *(uint4*)&cuy[(row0 + r)*192 + seg*8] = *(const uint4*)&ct[r*200 + seg*8];
  }

  // ---- phase B: layer1 + head partials
  for (int rf = 0; rf < 8; ++rf){
    f32x4 acc = {b1v, b1v, b1v, b1v};
    #pragma unroll
    for (int kk = 0; kk < 2; ++kk){
      short8v af = *(const short8v*)&h0l[(rf*16 + lr)*80 + kk*32 + lk];
      acc = __builtin_amdgcn_mfma_f32_16x16x32_bf16(af, bw1[kk], acc, 0, 0, 0);
    }
    float4 vpart;
    #pragma unroll
    for (int j = 0; j < 4; ++j) (&vpart.x)[j] = tanhf(acc[j]) * w2v;
    #pragma unroll
    for (int m = 1; m < 16; m <<= 1){
      vpart.x += __shfl_xor(vpart.x, m);
      vpart.y += __shfl_xor(vpart.y, m);
      vpart.z += __shfl_xor(vpart.z, m);
      vpart.w += __shfl_xor(vpart.w, m);
    }
    if (lr == 0){
      int orow = rf*16 + (lane >> 4)*4;
      #pragma unroll
      for (int j = 0; j < 4; ++j) pl[orow + j][w] = (&vpart.x)[j];
    }
  }
  __syncthreads();

  // ---- value + log_stds writes
  if (tid < 128)
    out[(size_t)VOFF + row0 + tid] = pl[tid][0] + pl[tid][1] + pl[tid][2] + pl[tid][3] + b2g[0];
  for (int li = tid; li < 128*16; li += 256){
    int r = li >> 4, c4 = li & 15;
    float4 lv = *(const float4*)&ls[c4*4];
    *(float4*)&out[(row0 + r)*128 + 64 + c4*4] = lv;
  }
}

// ---------------- phase 1 (MFMA): per-chunk zero-init scan -> deltas D[ci][b][s]
__global__ __launch_bounds__(256) void k_phase1(const unsigned short* __restrict__ cuy,
                                                const unsigned short* __restrict__ Mmibf,
                                                float* __restrict__ Dd){
  __shared__ __align__(16) unsigned short xw[32*136];
  int tid = threadIdx.x;
  int lane = tid & 63, w = tid >> 6;
  int lr = lane & 15, lg = lane >> 4;
  int ci = blockIdx.x >> 2, bi = blockIdx.x & 3;
  int b0 = bi*32, t0 = ci*K_CH;
  int colbase = w*32;

  short8v bm[2][4];                            // M-I columns, resident
  #pragma unroll
  for (int ctt = 0; ctt < 2; ++ctt)
    #pragma unroll
    for (int kk = 0; kk < 4; ++kk){
      short8v b;
      #pragma unroll
      for (int j = 0; j < 8; ++j)
        b[j] = (short)Mmibf[(size_t)(kk*32 + lg*8 + j)*128 + colbase + ctt*16 + lr];
      bm[ctt][kk] = b;
    }

  f32x4 acc[2][2];                             // x_1 = c_{t0}
  #pragma unroll
  for (int rt = 0; rt < 2; ++rt)
    #pragma unroll
    for (int ctt = 0; ctt < 2; ++ctt)
      #pragma unroll
      for (int j = 0; j < 4; ++j)
        acc[rt][ctt][j] = bf2f(cuy[((size_t)(b0 + rt*16 + lg*4 + j)*T_ + t0)*192 + colbase + ctt*16 + lr]);

  for (int s = 1; s < K_CH; ++s){
    unsigned short cn[2][2][4];
    #pragma unroll
    for (int rt = 0; rt < 2; ++rt)
      #pragma unroll
      for (int ctt = 0; ctt < 2; ++ctt)
        #pragma unroll
        for (int j = 0; j < 4; ++j)
          cn[rt][ctt][j] = cuy[((size_t)(b0 + rt*16 + lg*4 + j)*T_ + t0 + s)*192 + colbase + ctt*16 + lr];
    #pragma unroll
    for (int rt = 0; rt < 2; ++rt)
      #pragma unroll
      for (int ctt = 0; ctt < 2; ++ctt)
        #pragma unroll
        for (int j = 0; j < 4; ++j)
          xw[(rt*16 + lg*4 + j)*136 + colbase + ctt*16 + lr] = f2bf(acc[rt][ctt][j]);
    __syncthreads();
    short8v af[2][4];
    #pragma unroll
    for (int rt = 0; rt < 2; ++rt)
      #pragma unroll
      for (int kk = 0; kk < 4; ++kk)
        af[rt][kk] = *(const short8v*)&xw[(rt*16 + lr)*136 + kk*32 + lg*8];
    __syncthreads();
    #pragma unroll
    for (int rt = 0; rt < 2; ++rt)
      #pragma unroll
      for (int ctt = 0; ctt < 2; ++ctt)
        #pragma unroll
        for (int kk = 0; kk < 4; ++kk)
          acc[rt][ctt] = __builtin_amdgcn_mfma_f32_16x16x32_bf16(af[rt][kk], bm[ctt][kk], acc[rt][ctt], 0, 0, 0);
    #pragma unroll
    for (int rt = 0; rt < 2; ++rt)
      #pragma unroll
      for (int ctt = 0; ctt < 2; ++ctt)
        #pragma unroll
        for (int j = 0; j < 4; ++j)
          acc[rt][ctt][j] += bf2f(cn[rt][ctt][j]);
  }
  #pragma unroll
  for (int rt = 0; rt < 2; ++rt)
    #pragma unroll
    for (int ctt = 0; ctt < 2; ++ctt)
      #pragma unroll
      for (int j = 0; j < 4; ++j)
        Dd[(size_t)ci*16384 + (size_t)(b0 + rt*16 + lg*4 + j)*128 + colbase + ctt*16 + lr] = acc[rt][ctt][j];
}

// ---------------- combine: sequential over 64 chunks, parallel over batch rows
__global__ __launch_bounds__(256) void k_combine(const float* __restrict__ Mk,
                                                 const float* __restrict__ Dd,
                                                 const float* __restrict__ x0,
                                                 float* __restrict__ XS,
                                                 float* __restrict__ xfin){
  __shared__ float xl[128];
  __shared__ float pl[256];
  int tid = threadIdx.x;
  int b = blockIdx.x;
  int c = tid & 127, h = tid >> 7;
  float mreg[64];
  #pragma unroll
  for (int j = 0; j < 64; ++j) mreg[j] = Mk[(64*h + j)*128 + c];
  if (tid < 128) xl[tid] = x0[(size_t)b*128 + tid];
  __syncthreads();
  for (int i = 0; i < C_CH; ++i){
    if (tid < 128) XS[(size_t)i*16384 + (size_t)b*128 + tid] = xl[tid];
    float part = 0.f;
    #pragma unroll
    for (int jj = 0; jj < 64; jj += 4){
      float4 xv = *(const float4*)&xl[64*h + jj];
      part += xv.x*mreg[jj] + xv.y*mreg[jj+1] + xv.z*mreg[jj+2] + xv.w*mreg[jj+3];
    }
    pl[tid] = part;
    __syncthreads();
    if (tid < 128)
      xl[tid] = pl[tid] + pl[tid + 128] + Dd[(size_t)i*16384 + (size_t)b*128 + tid];
    __syncthreads();
  }
  if (tid < 128) xfin[(size_t)b*128 + tid] = xl[tid];
}

// ---------------- phase 3 (MFMA): replay with true inits, fused action output
__global__ __launch_bounds__(256) void k_phase3(const unsigned short* __restrict__ cuy,
                                                const unsigned short* __restrict__ Mmibf,
                                                const unsigned short* __restrict__ cubf,
                                                const float* __restrict__ XS,
                                                float* __restrict__ out){
  __shared__ __align__(16) unsigned short xw[32*136];
  int tid = threadIdx.x;
  int lane = tid & 63, w = tid >> 6;
  int lr = lane & 15, lg = lane >> 4;
  int ci = blockIdx.x >> 2, bi = blockIdx.x & 3;
  int b0 = bi*32, t0 = ci*K_CH;
  int colbase = w*32;
  int ucolbase = w*16;

  short8v bm[2][4];
  #pragma unroll
  for (int ctt = 0; ctt < 2; ++ctt)
    #pragma unroll
    for (int kk = 0; kk < 4; ++kk){
      short8v b;
      #pragma unroll
      for (int j = 0; j < 8; ++j)
        b[j] = (short)Mmibf[(size_t)(kk*32 + lg*8 + j)*128 + colbase + ctt*16 + lr];
      bm[ctt][kk] = b;
    }
  short8v bc[4];                               // Cu columns, resident
  #pragma unroll
  for (int kk = 0; kk < 4; ++kk){
    short8v b;
    #pragma unroll
    for (int j = 0; j < 8; ++j)
      b[j] = (short)cubf[(size_t)(kk*32 + lg*8 + j)*64 + ucolbase + lr];
    bc[kk] = b;
  }

  f32x4 acc[2][2];                             // x_{t0} from combine (f32)
  #pragma unroll
  for (int rt = 0; rt < 2; ++rt)
    #pragma unroll
    for (int ctt = 0; ctt < 2; ++ctt)
      #pragma unroll
      for (int j = 0; j < 4; ++j)
        acc[rt][ctt][j] = XS[(size_t)ci*16384 + (size_t)(b0 + rt*16 + lg*4 + j)*128 + colbase + ctt*16 + lr];

  for (int s = 0; s < K_CH; ++s){
    f32x4 au[2];                               // u = uy + x@Cu
    #pragma unroll
    for (int rt = 0; rt < 2; ++rt)
      #pragma unroll
      for (int j = 0; j < 4; ++j)
        au[rt][j] = bf2f(cuy[((size_t)(b0 + rt*16 + lg*4 + j)*T_ + t0 + s)*192 + 128 + ucolbase + lr]);
    unsigned short cn[2][2][4];
    if (s + 1 < K_CH){
      #pragma unroll
      for (int rt = 0; rt < 2; ++rt)
        #pragma unroll
        for (int ctt = 0; ctt < 2; ++ctt)
          #pragma unroll
          for (int j = 0; j < 4; ++j)
            cn[rt][ctt][j] = cuy[((size_t)(b0 + rt*16 + lg*4 + j)*T_ + t0 + s)*192 + colbase + ctt*16 + lr];
    }
    #pragma unroll
    for (int rt = 0; rt < 2; ++rt)
      #pragma unroll
      for (int ctt = 0; ctt < 2; ++ctt)
        #pragma unroll
        for (int j = 0; j < 4; ++j)
          xw[(rt*16 + lg*4 + j)*136 + colbase + ctt*16 + lr] = f2bf(acc[rt][ctt][j]);
    __syncthreads();
    short8v af[2][4];
    #pragma unroll
    for (int rt = 0; rt < 2; ++rt)
      #pragma unroll
      for (int kk = 0; kk < 4; ++kk)
        af[rt][kk] = *(const short8v*)&xw[(rt*16 + lr)*136 + kk*32 + lg*8];
    __syncthreads();
    // u output
    #pragma unroll
    for (int rt = 0; rt < 2; ++rt)
      #pragma unroll
      for (int kk = 0; kk < 4; ++kk)
        au[rt] = __builtin_amdgcn_mfma_f32_16x16x32_bf16(af[rt][kk], bc[kk], au[rt], 0, 0, 0);
    #pragma unroll
    for (int rt = 0; rt < 2; ++rt)
      #pragma unroll
      for (int j = 0; j < 4; ++j)
        out[((size_t)(b0 + rt*16 + lg*4 + j)*T_ + t0 + s)*128 + ucolbase + lr] = au[rt][j];
    // x update (skip on last step)
    if (s + 1 < K_CH){
      #pragma unroll
      for (int rt = 0; rt < 2; ++rt)
        #pragma unroll
        for (int ctt = 0; ctt < 2; ++ctt)
          #pragma unroll
          for (int kk = 0; kk < 4; ++kk)
            acc[rt][ctt] = __builtin_amdgcn_mfma_f32_16x16x32_bf16(af[rt][kk], bm[ctt][kk], acc[rt][ctt], 0, 0, 0);
      #pragma unroll
      for (int rt = 0; rt < 2; ++rt)
        #pragma unroll
        for (int ctt = 0; ctt < 2; ++ctt)
          #pragma unroll
          for (int j = 0; j < 4; ++j)
            acc[rt][ctt][j] += bf2f(cn[rt][ctt][j]);
    }
  }
}

extern "C" void kernel_launch(void* const* d_in, const int* in_sizes, int n_in,
                              void* d_out, int out_size, void* d_ws, size_t ws_size,
                              hipStream_t stream){
  const float* obs  = (const float*)d_in[0];
  const float* x0   = (const float*)d_in[1];
  const float* A_T  = (const float*)d_in[2];
  const float* By_T = (const float*)d_in[3];
  const float* Cu_T = (const float*)d_in[4];
  const float* Duy_T= (const float*)d_in[5];
  const float* ls   = (const float*)d_in[6];
  const float* W0   = (const float*)d_in[7];
  const float* b0   = (const float*)d_in[8];
  const float* W1   = (const float*)d_in[9];
  const float* b1   = (const float*)d_in[10];
  const float* W2   = (const float*)d_in[11];
  const float* b2   = (const float*)d_in[12];
  const float* dt   = (const float*)d_in[13];
  float* out = (float*)d_out;

  char* ws = (char*)d_ws;
  unsigned short* cuy = (unsigned short*)(ws + 0);            // 100663296 B
  float* A2     = (float*)(ws + 100663296);                   // 65536 each
  float* A3     = (float*)(ws + 100728832);
  float* A4     = (float*)(ws + 100794368);
  float* Mm     = (float*)(ws + 100859904);
  float* Pp     = (float*)(ws + 100925440);
  float* Mk     = (float*)(ws + 100990976);
  float* sq1    = (float*)(ws + 101056512);
  float* sq2    = (float*)(ws + 101122048);
  unsigned short* Mmibf = (unsigned short*)(ws + 101187584);  // 32768 B
  float* Wcat   = (float*)(ws + 101255168);                   // 98304 B
  unsigned short* cubf  = (unsigned short*)(ws + 101353472);  // 16384 B
  float* Dd     = (float*)(ws + 101387264);                   // 4194304 B
  float* XS     = (float*)(ws + 105581568);                   // 4194304 B
  unsigned short* Wbf  = (unsigned short*)Pp;                 // Pp dead after G (49152 B)
  unsigned short* W0bf = (unsigned short*)sq2;                // sq2 dead after Mk (16384 B)
  unsigned short* W1bf = (unsigned short*)(((char*)sq2) + 16384); // 8192 B

  // ---- small setup chain (Mk chain first so sq1/sq2 free before k_cvtw)
  k_mm<<<64, 256, 0, stream>>>(A_T, A_T, A2, 128);
  k_mm<<<64, 256, 0, stream>>>(A2, A_T, A3, 128);
  k_mm<<<64, 256, 0, stream>>>(A2, A2, A4, 128);
  k_build<<<64, 256, 0, stream>>>(A_T, A2, A3, A4, Cu_T, Duy_T, dt, Mm, Mmibf, Pp, Wcat, cubf);
  k_mm<<<64, 256, 0, stream>>>(By_T, Pp, Wcat, 192);          // G -> Wcat cols 0..127
  k_mm<<<64, 256, 0, stream>>>(Mm, Mm, sq1, 128);             // M^2
  k_mm<<<64, 256, 0, stream>>>(sq1, sq1, sq2, 128);           // M^4
  k_mm<<<64, 256, 0, stream>>>(sq2, sq2, sq1, 128);           // M^8
  k_mm<<<64, 256, 0, stream>>>(sq1, sq1, sq2, 128);           // M^16
  k_mm<<<64, 256, 0, stream>>>(sq2, sq2, Mk, 128);            // M^32
  k_cvtw<<<144, 256, 0, stream>>>(Wcat, W0, W1, Wbf, W0bf, W1bf); // Pp/sq2 dead now

  // ---- big parallel work
  k_fused<<<NR/128, 256, 0, stream>>>(obs, Wbf, W0bf, W1bf, W2, b0, b1, b2, ls, cuy, out);
  k_phase1<<<C_CH*4, 256, 0, stream>>>(cuy, Mmibf, Dd);
  k_combine<<<B_, 256, 0, stream>>>(Mk, Dd, x0, XS, out + XFOFF);
  k_phase3<<<C_CH*4, 256, 0, stream>>>(cuy, Mmibf, cubf, XS, out);
}